// Round 11
// baseline (110.713 us; speedup 1.0000x reference)
//
#include <hip/hip_runtime.h>
#include <math.h>

#define R 1000
#define NC 81
#define CAP 1024       // >= R, so compaction can never overflow
#define NT 512
#define SUPMAX 512     // matrix-NMS path handles V <= SUPMAX
#define WMAX 8         // SUPMAX / 64 keep-words
#define TROWS 256      // rows per LDS tile
#define NTILE ((R + TROWS - 1) / TROWS)

// Union offsets (bytes) inside s_u. Tile buffer (phase 1) overlaps all
// phase-2+ arrays; s_score/s_idx/s_cnt live across the phase boundary and
// are kept separate.
#define U_SS    0                         // float[CAP]
#define U_Y0    (4096)
#define U_X0    (8192)
#define U_Y1    (12288)
#define U_X1    (16384)
#define U_AREA  (20480)
#define U_KEEPI (24576)                   // int[CAP]
#define U_SUP   (28672)                   // ull[SUPMAX*WMAX] = 32768 B
#define U_KW    (61440)                   // ull[WMAX]
#define U_BYTES (TROWS * NC * 4)          // 82944 B: tile is the max user

// ONE kernel node, block = class. Phase 1: score matrix staged through LDS in
// 256-row tiles with COALESCED loads (R10's thread-per-row direct reads
// gathered 64 distinct cache lines per instruction -> ~830MB of L2 line
// traffic; staging cuts it to 26MB). Max/sum per row then read from LDS
// (bank stride 81%32=17, coprime -> free 2-way). Early-out is exact:
// sum(exp) >= 1, so exp(x_c - m) <= 0.05 => p < 0.05.
__global__ __launch_bounds__(NT) void frcnn_fused3_kernel(
    const float* __restrict__ roi,        // [R,4]  (ymin,xmin,ymax,xmax)
    const float* __restrict__ roi_loc,    // [R, NC*4]
    const float* __restrict__ roi_score,  // [R, NC]
    float* __restrict__ out)              // [80*R*5] boxes+score, then [80*R] labels
{
    const int c   = blockIdx.x + 1;       // class 1..80
    const int tid = threadIdx.x;

    __shared__ __align__(16) char s_u[U_BYTES];
    __shared__ float s_score[CAP];
    __shared__ int   s_idx[CAP];
    __shared__ int   s_cnt;

    float* s_tile  = (float*)s_u;                        // phase 1 only
    float* s_ss    = (float*)(s_u + U_SS);               // phase 2+
    float* s_y0    = (float*)(s_u + U_Y0);
    float* s_x0    = (float*)(s_u + U_X0);
    float* s_y1    = (float*)(s_u + U_Y1);
    float* s_x1    = (float*)(s_u + U_X1);
    float* s_area  = (float*)(s_u + U_AREA);
    int*   s_keepi = (int*)(s_u + U_KEEPI);
    unsigned long long* s_sup = (unsigned long long*)(s_u + U_SUP);
    unsigned long long* s_kw  = (unsigned long long*)(s_u + U_KW);

    if (tid == 0) s_cnt = 0;
    __syncthreads();

    // ---- 1. tiled softmax prob for class c; compact into s_score/s_idx ----
    for (int t = 0; t < NTILE; ++t) {
        const int r0   = t * TROWS;
        const int rows = (R - r0 < TROWS) ? (R - r0) : TROWS;
        const int n    = rows * NC;
        const float* src = roi_score + (size_t)r0 * NC;
        for (int i = tid; i < n; i += NT)        // coalesced contiguous load
            s_tile[i] = src[i];
        __syncthreads();
        if (tid < rows) {
            const float* row = s_tile + tid * NC;
            float m = row[0];
            #pragma unroll
            for (int k = 1; k < NC; ++k) m = fmaxf(m, row[k]);
            float num = expf(row[c] - m);
            float p = 0.0f;
            if (num > 0.05f) {                   // exact early-out (sum >= 1)
                float sum = 0.0f;
                for (int k = 0; k < NC; ++k) sum += expf(row[k] - m);
                p = num / sum;
            }
            if (p > 0.05f) {
                int slot = atomicAdd(&s_cnt, 1); // LDS atomic
                s_score[slot] = p;
                s_idx[slot]   = r0 + tid;
            }
        }
        __syncthreads();                         // tile dead before overwrite
    }
    const int V = s_cnt;

    // ---- 2. rank-sort (stable argsort by (-score, idx)) + fused decode ----
    for (int p = tid; p < V; p += NT) {
        float sp = s_score[p];
        int   ip = s_idx[p];
        int rank = 0;
        for (int q = 0; q < V; ++q) {
            float sq = s_score[q];
            int   iq = s_idx[q];
            rank += (sq > sp) || (sq == sp && iq < ip);
        }
        float ry0 = roi[ip*4+0], rx0 = roi[ip*4+1];
        float ry1 = roi[ip*4+2], rx1 = roi[ip*4+3];
        float h = ry1 - ry0, w = rx1 - rx0;
        float cy = ry0 + 0.5f*h, cx = rx0 + 0.5f*w;
        const float* lp = roi_loc + (size_t)ip*(NC*4) + c*4;
        float dy = lp[0]*0.1f, dx = lp[1]*0.1f;
        float dh = lp[2]*0.2f, dw = lp[3]*0.2f;
        float ny = dy*h + cy, nx = dx*w + cx;
        float nh = expf(dh)*h, nw = expf(dw)*w;
        float y0 = ny - 0.5f*nh, x0 = nx - 0.5f*nw;
        float y1 = ny + 0.5f*nh, x1 = nx + 0.5f*nw;
        y0 = fminf(fmaxf(y0, 0.f), 600.f);
        x0 = fminf(fmaxf(x0, 0.f), 800.f);
        y1 = fminf(fmaxf(y1, 0.f), 600.f);
        x1 = fminf(fmaxf(x1, 0.f), 800.f);
        s_ss[rank] = sp;
        s_y0[rank] = y0; s_x0[rank] = x0; s_y1[rank] = y1; s_x1[rank] = x1;
        s_area[rank] = (y1 - y0) * (x1 - x0);
        s_keepi[rank] = 1;
    }
    __syncthreads();

    // ---- 3. NMS ----
    if (V > 0 && V <= SUPMAX) {
        const int W = (V + 63) >> 6;
        // 3a. suppression bit-matrix, one row per thread
        for (int i = tid; i < V; i += NT) {
            float ay0 = s_y0[i], ax0 = s_x0[i];
            float ay1 = s_y1[i], ax1 = s_x1[i];
            float aa  = s_area[i];
            for (int w = 0; w < W; ++w) {
                int j0 = w * 64;
                int js = (i + 1 > j0) ? i + 1 : j0;
                int je = (j0 + 64 < V) ? j0 + 64 : V;
                unsigned long long bits = 0ull;
                for (int j = js; j < je; ++j) {
                    float ty = fmaxf(ay0, s_y0[j]);
                    float tx = fmaxf(ax0, s_x0[j]);
                    float by = fminf(ay1, s_y1[j]);
                    float bx = fminf(ax1, s_x1[j]);
                    float hh = fmaxf(by - ty, 0.f);
                    float ww = fmaxf(bx - tx, 0.f);
                    float inter = hh * ww;
                    float iou = inter / (aa + s_area[j] - inter + 1e-9f);
                    if (iou > 0.5f) bits |= (1ull << (j - j0));
                }
                s_sup[i * W + w] = bits;
            }
        }
        __syncthreads();
        // 3b. serial scan in thread-0 registers, next row prefetched
        if (tid == 0) {
            unsigned long long kw[WMAX];
            #pragma unroll
            for (int w = 0; w < WMAX; ++w) {
                int full = V - w * 64;
                kw[w] = (full >= 64) ? ~0ull : (full > 0 ? ((1ull << full) - 1ull) : 0ull);
            }
            unsigned long long rowb[WMAX], nxtb[WMAX];
            #pragma unroll
            for (int w = 0; w < WMAX; ++w) rowb[w] = (w < W) ? s_sup[w] : 0ull;
            #pragma unroll
            for (int w = 0; w < WMAX; ++w) {
                if (w * 64 < V) {
                    unsigned long long cur = kw[w];
                    int lim = V - w * 64; if (lim > 64) lim = 64;
                    for (int b = 0; b < lim; ++b) {
                        int nxt = w * 64 + b + 1;           // prefetch next row
                        if (nxt < V) {
                            #pragma unroll
                            for (int w2 = 0; w2 < WMAX; ++w2)
                                if (w2 < W) nxtb[w2] = s_sup[nxt * W + w2];
                        }
                        if ((cur >> b) & 1ull) {
                            cur &= ~rowb[w];
                            #pragma unroll
                            for (int w2 = 0; w2 < WMAX; ++w2)
                                if (w2 > w && w2 < W) kw[w2] &= ~rowb[w2];
                        }
                        #pragma unroll
                        for (int w2 = 0; w2 < WMAX; ++w2) rowb[w2] = nxtb[w2];
                    }
                    kw[w] = cur;
                }
            }
            #pragma unroll
            for (int w = 0; w < WMAX; ++w) s_kw[w] = kw[w];
        }
        __syncthreads();
    } else if (V > SUPMAX) {
        // fallback: sequential-i / parallel-j greedy (correct for any V)
        for (int i = 0; i < V; ++i) {
            if (s_keepi[i]) {
                float ay0 = s_y0[i], ax0 = s_x0[i];
                float ay1 = s_y1[i], ax1 = s_x1[i];
                float aa  = s_area[i];
                for (int jj = i + 1 + tid; jj < V; jj += NT) {
                    float ty = fmaxf(ay0, s_y0[jj]);
                    float tx = fmaxf(ax0, s_x0[jj]);
                    float by = fminf(ay1, s_y1[jj]);
                    float bx = fminf(ax1, s_x1[jj]);
                    float hh = fmaxf(by - ty, 0.f);
                    float ww = fmaxf(bx - tx, 0.f);
                    float inter = hh * ww;
                    float iou = inter / (aa + s_area[jj] - inter + 1e-9f);
                    if (iou > 0.5f) s_keepi[jj] = 0;
                }
            }
            __syncthreads();
        }
    }

    // ---- 4. write outputs (covers full buffer; no memset needed) ----
    const bool matrix_path = (V <= SUPMAX);
    float* out0 = out + (size_t)(c - 1) * R * 5;
    float* out1 = out + (size_t)80 * R * 5 + (size_t)(c - 1) * R;
    for (int p = tid; p < R; p += NT) {
        bool kept = false;
        if (p < V)
            kept = matrix_path ? (((s_kw[p >> 6] >> (p & 63)) & 1ull) != 0ull)
                               : (s_keepi[p] != 0);
        float y0 = 0.f, x0 = 0.f, y1 = 0.f, x1 = 0.f, s = 0.f, lab = -1.0f;
        if (kept) {
            y0 = s_y0[p]; x0 = s_x0[p]; y1 = s_y1[p]; x1 = s_x1[p];
            s  = s_ss[p];
            lab = (float)(c - 1);
        }
        out0[p*5+0] = y0; out0[p*5+1] = x0; out0[p*5+2] = y1;
        out0[p*5+3] = x1; out0[p*5+4] = s;
        out1[p] = lab;
    }
}

extern "C" void kernel_launch(void* const* d_in, const int* in_sizes, int n_in,
                              void* d_out, int out_size, void* d_ws, size_t ws_size,
                              hipStream_t stream) {
    const float* roi       = (const float*)d_in[0];
    const float* roi_loc   = (const float*)d_in[1];
    const float* roi_score = (const float*)d_in[2];
    float* out = (float*)d_out;

    hipLaunchKernelGGL(frcnn_fused3_kernel, dim3(NC - 1), dim3(NT), 0, stream,
                       roi, roi_loc, roi_score, out);
}